// Round 8
// baseline (79.753 us; speedup 1.0000x reference)
//
#include <hip/hip_runtime.h>

#define B     4096
#define KNB   64
#define D     128
#define NREL  32
#define EPS   1e-5f

typedef __attribute__((ext_vector_type(8))) short bf16x8;
typedef __attribute__((ext_vector_type(4))) float f32x4;

__device__ inline unsigned short f2bf(float f) {
    unsigned u = __float_as_uint(f);
    return (unsigned short)((u + 0x7FFFu + ((u >> 16) & 1u)) >> 16);
}
// HW packed convert, RTNE — bit-identical to f2bf, 1 VALU op per 2 floats.
__device__ inline unsigned cvt_pk_bf16(float lo, float hi) {
    unsigned r;
    asm("v_cvt_pk_bf16_f32 %0, %1, %2" : "=v"(r) : "v"(lo), "v"(hi));
    return r;
}
__device__ inline unsigned short cvt1_bf16(float f) {
    return (unsigned short)(cvt_pk_bf16(f, f) & 0xFFFFu);
}
__device__ inline float bfu_lo(unsigned u) { return __uint_as_float(u << 16); }
__device__ inline float bfu_hi(unsigned u) { return __uint_as_float(u & 0xFFFF0000u); }

// tanh(x) = 1 - 2/(exp(2x)+1), exp via native v_exp_f32. |err| ~1e-6.
__device__ inline float fast_tanh(float x) {
    float e = __builtin_amdgcn_exp2f(x * 2.885390082f);   // 2*log2(e)
    return 1.f - 2.f * __builtin_amdgcn_rcpf(e + 1.f);
}

// ---------------------------------------------------------------------------
// prep (grid=1): Wt = bf16(Wr1^T);  scale/shift = folded BN affine.
// ---------------------------------------------------------------------------
__global__ __launch_bounds__(256) void prep(
    const float* __restrict__ W, unsigned short* __restrict__ Wt,
    const float* __restrict__ gamma, const float* __restrict__ beta,
    const float* __restrict__ mean,  const float* __restrict__ var,
    float* __restrict__ scale, float* __restrict__ shift)
{
    const int t = threadIdx.x;
    #pragma unroll
    for (int m = 0; m < 64; ++m) {
        const int idx = m * 256 + t;
        const int k = idx >> 7, n = idx & 127;
        Wt[n * D + k] = f2bf(W[idx]);
    }
    if (t < D) {
        const float sc = gamma[t] * rsqrtf(var[t] + EPS);
        scale[t] = sc;
        shift[t] = beta[t] - mean[t] * sc;
    }
}

// ---------------------------------------------------------------------------
// MFMA GEMM, 16x16x32 bf16, tile 64 rows x 128 cols, 4 waves.
// blocks <  nb1 : Etr = bf16( embs @ W + bias )        (bf16 bounce-store)
// blocks >= nb1 : h0  = bn(embs[{i,u}]) (f32, stored)  AND
//                 hW  = h0 @ W + bias   (f32 direct store)
// ---------------------------------------------------------------------------
__global__ __launch_bounds__(256) void gemm_etr(
    const float* __restrict__ embs, const unsigned short* __restrict__ Wt,
    const float* __restrict__ bias, unsigned short* __restrict__ outbf,
    const int* __restrict__ i_idx, const int* __restrict__ u_idx,
    const float* __restrict__ scale, const float* __restrict__ shift,
    float* __restrict__ h0out, float* __restrict__ out2, int nb1)
{
    __shared__ unsigned short Al[64 * 128];    // 16 KB
    __shared__ unsigned short Wl[128 * 128];   // 32 KB

    const int t = threadIdx.x;
    const bool second = (int)blockIdx.x >= nb1;
    const size_t row0 = (size_t)(second ? (int)blockIdx.x - nb1 : (int)blockIdx.x) * 64;

    {
        const float4* w4 = (const float4*)Wt;
        #pragma unroll
        for (int m = 0; m < 8; ++m) {
            const int c = m * 256 + t;
            const int n = c >> 4;
            float4 v = w4[c];
            *(float4*)((char*)Wl + ((c * 16) ^ ((n & 7) << 4))) = v;
        }
    }
    if (!second) {
        #pragma unroll
        for (int m = 0; m < 4; ++m) {
            const int c = m * 256 + t;
            const int r = c >> 4;
            const int k0 = (c & 15) * 8;
            const float4* s = (const float4*)&embs[(row0 + r) * D + k0];
            const float4 x = s[0], y = s[1];
            uint4 h;
            h.x = cvt_pk_bf16(x.x, x.y);
            h.y = cvt_pk_bf16(x.z, x.w);
            h.z = cvt_pk_bf16(y.x, y.y);
            h.w = cvt_pk_bf16(y.z, y.w);
            *(uint4*)((char*)Al + ((r * 256 + k0 * 2) ^ ((r & 7) << 4))) = h;
        }
    } else {
        // bn-fold: gather embs[idx_j[b]], apply scale/shift, store h0, stage bf16
        #pragma unroll
        for (int m = 0; m < 4; ++m) {
            const int c = m * 256 + t;
            const int r = c >> 4;
            const int k0 = (c & 15) * 8;
            const int grow = (int)row0 + r;              // 0 .. 2B-1
            const int bb = grow & (B - 1);
            const int idxv = (grow >= B) ? u_idx[bb] : i_idx[bb];
            const float4* s = (const float4*)&embs[(size_t)idxv * D + k0];
            const float4 x = s[0], y = s[1];
            const float4 sc0 = *(const float4*)&scale[k0];
            const float4 sc1 = *(const float4*)&scale[k0 + 4];
            const float4 sh0 = *(const float4*)&shift[k0];
            const float4 sh1 = *(const float4*)&shift[k0 + 4];
            float4 a0, a1;
            a0.x = fmaf(x.x, sc0.x, sh0.x); a0.y = fmaf(x.y, sc0.y, sh0.y);
            a0.z = fmaf(x.z, sc0.z, sh0.z); a0.w = fmaf(x.w, sc0.w, sh0.w);
            a1.x = fmaf(y.x, sc1.x, sh1.x); a1.y = fmaf(y.y, sc1.y, sh1.y);
            a1.z = fmaf(y.z, sc1.z, sh1.z); a1.w = fmaf(y.w, sc1.w, sh1.w);
            *(float4*)&h0out[(size_t)grow * D + k0]     = a0;
            *(float4*)&h0out[(size_t)grow * D + k0 + 4] = a1;
            uint4 h;
            h.x = cvt_pk_bf16(a0.x, a0.y);
            h.y = cvt_pk_bf16(a0.z, a0.w);
            h.z = cvt_pk_bf16(a1.x, a1.y);
            h.w = cvt_pk_bf16(a1.z, a1.w);
            *(uint4*)((char*)Al + ((r * 256 + k0 * 2) ^ ((r & 7) << 4))) = h;
        }
    }
    __syncthreads();

    const int wv   = t >> 6;
    const int lane = t & 63;
    const int rw   = wv * 16;
    const int lrow = lane & 15;
    const int kgrp = lane >> 4;

    f32x4 acc[8];
    #pragma unroll
    for (int n = 0; n < 8; ++n) acc[n] = (f32x4){0.f, 0.f, 0.f, 0.f};

    #pragma unroll
    for (int ks = 0; ks < 4; ++ks) {
        const int arow = rw + lrow;
        const bf16x8 a = *(const bf16x8*)((const char*)Al +
            ((arow * 256 + ks * 64 + kgrp * 16) ^ ((arow & 7) << 4)));
        #pragma unroll
        for (int n = 0; n < 8; ++n) {
            const int brow = n * 16 + lrow;
            const bf16x8 b = *(const bf16x8*)((const char*)Wl +
                ((brow * 256 + ks * 64 + kgrp * 16) ^ ((brow & 7) << 4)));
            acc[n] = __builtin_amdgcn_mfma_f32_16x16x32_bf16(a, b, acc[n], 0, 0, 0);
        }
    }

    // C/D layout: col = lane&15, row = (lane>>4)*4 + i
    if (second) {   // hW f32 direct store
        #pragma unroll
        for (int n = 0; n < 8; ++n) {
            const float bv = bias[n * 16 + lrow];
            #pragma unroll
            for (int i = 0; i < 4; ++i) {
                const size_t r = row0 + rw + kgrp * 4 + i;
                out2[r * D + n * 16 + lrow] = acc[n][i] + bv;
            }
        }
        return;
    }

    __syncthreads();
    #pragma unroll
    for (int n = 0; n < 8; ++n) {
        const float bv = bias[n * 16 + lrow];
        #pragma unroll
        for (int i = 0; i < 4; ++i) {
            const int r = rw + kgrp * 4 + i;
            const int cb = (r * 256 + (n * 16 + lrow) * 2) ^ ((r & 7) << 4);
            *(unsigned short*)((char*)Al + cb) = cvt1_bf16(acc[n][i] + bv);
        }
    }
    __syncthreads();
    {
        float4* dst = (float4*)(outbf + row0 * D);
        #pragma unroll
        for (int m = 0; m < 4; ++m) {
            const int c = m * 256 + t;
            const int r = c >> 4;
            dst[c] = *(const float4*)((const char*)Al + ((c * 16) ^ ((r & 7) << 4)));
        }
    }
}

// ---------------------------------------------------------------------------
// aggregate v6: ps/pq alias dead tt space -> LDS 16.5 KB (8 blocks/CU if
// VGPR allows); gathers issue before tanh table (latency hidden); h0 row
// prefetched early.
// ---------------------------------------------------------------------------
__global__ __launch_bounds__(256, 6) void aggregate(
    const int* __restrict__ i_idx, const int* __restrict__ u_idx,
    const int* __restrict__ adj_e, const int* __restrict__ adj_r,
    const unsigned short* __restrict__ Etr, const float* __restrict__ rel_embs,
    const float* __restrict__ hW,  const float* __restrict__ h0,
    float* __restrict__ g_out)
{
    __shared__ float tt[NREL * D];    // 16 KB; reused for ps/pq after main loop
    __shared__ int ents[KNB];
    __shared__ int rels[KNB];
    float* ps = tt;                   // [4][D]
    float* pq = tt + 4 * D;           // [4][D]

    const int t = threadIdx.x;
    const int b = blockIdx.x & (B - 1);
    const int j = blockIdx.x >> 12;
    const size_t rowbase = ((size_t)j * B + b) * D;
    const int idx = j ? u_idx[b] : i_idx[b];

    // early loads: hW chunk (table build) + h0 element (epilogue)
    const float4 hv = *(const float4*)&hW[rowbase + (t & 31) * 4];
    float h0v = 0.f;
    if (t < D) h0v = h0[rowbase + t];

    if (t < KNB) {
        ents[t] = adj_e[(size_t)idx * KNB + t] * (D * 2);
        rels[t] = adj_r[(size_t)idx * KNB + t] * (D * 4);
    }
    __syncthreads();   // ents/rels ready

    const int dq  = t & 31;
    const int grp = t >> 5;
    const char* Eb = (const char*)Etr + dq * 8;
    const char* tb = (const char*)tt  + dq * 16;

    // issue ALL 8 random gathers; latency hides under the tanh-table pass.
    uint2 ev[8];
    #pragma unroll
    for (int it = 0; it < 8; ++it)
        ev[it] = *(const uint2*)(Eb + ents[grp + it * 8]);

    {
        const float4* re4 = (const float4*)rel_embs;
        #pragma unroll
        for (int c = 0; c < 4; ++c) {
            const int m4 = t + c * 256;
            const float4 r = re4[m4];
            float4 o;
            o.x = fast_tanh(hv.x + r.x);
            o.y = fast_tanh(hv.y + r.y);
            o.z = fast_tanh(hv.z + r.z);
            o.w = fast_tanh(hv.w + r.w);
            *(float4*)&tt[m4 * 4] = o;
        }
    }
    __syncthreads();   // tt ready

    float s0 = 0.f, s1 = 0.f, s2 = 0.f, s3 = 0.f;
    float q0 = 0.f, q1 = 0.f, q2 = 0.f, q3 = 0.f;
    #pragma unroll
    for (int it = 0; it < 8; ++it) {
        const float4 tv = *(const float4*)(tb + rels[grp + it * 8]);
        const float v0 = bfu_lo(ev[it].x) * tv.x;
        const float v1 = bfu_hi(ev[it].x) * tv.y;
        const float v2 = bfu_lo(ev[it].y) * tv.z;
        const float v3 = bfu_hi(ev[it].y) * tv.w;
        s0 += v0; s1 += v1; s2 += v2; s3 += v3;
        q0 = fmaf(v0, v0, q0); q1 = fmaf(v1, v1, q1);
        q2 = fmaf(v2, v2, q2); q3 = fmaf(v3, v3, q3);
    }
    s0 += __shfl_xor(s0, 32); s1 += __shfl_xor(s1, 32);
    s2 += __shfl_xor(s2, 32); s3 += __shfl_xor(s3, 32);
    q0 += __shfl_xor(q0, 32); q1 += __shfl_xor(q1, 32);
    q2 += __shfl_xor(q2, 32); q3 += __shfl_xor(q3, 32);

    __syncthreads();   // all tt reads done; safe to overwrite with ps/pq

    const int wv = t >> 6;
    if ((t & 63) < 32) {
        *(float4*)&ps[wv * D + dq * 4] = make_float4(s0, s1, s2, s3);
        *(float4*)&pq[wv * D + dq * 4] = make_float4(q0, q1, q2, q3);
    }
    __syncthreads();

    if (t < D) {
        const float ss = ps[t] + ps[D + t] + ps[2 * D + t] + ps[3 * D + t];
        const float qq = pq[t] + pq[D + t] + pq[2 * D + t] + pq[3 * D + t];
        g_out[rowbase + t] = h0v + ss * ss - qq;
    }
}

// ---------------------------------------------------------------------------
// gemm_fin: block handles 16 b's = rows {b0..b0+15} (j=0) + {B+b0..} (j=1).
// o = h0 + lrelu(gb @ W1 + b1); epilogue: per-row dot with wl segment,
// 32-lane shfl reduce, out[b] = wl_b + dot(j0,wl[128:]) + dot(j1,wl[0:128]).
// ---------------------------------------------------------------------------
__global__ __launch_bounds__(256) void gemm_fin(
    const float* __restrict__ gb, const float* __restrict__ W,
    const float* __restrict__ bias, const float* __restrict__ h0,
    const float* __restrict__ wl_w, const float* __restrict__ wl_b,
    float* __restrict__ out)
{
    __shared__ float Wl[128 * 128];   // 64 KB
    __shared__ float inl[32 * 128];   // 16 KB
    __shared__ float rowdot[32];
    const int t = threadIdx.x;
    const int b0 = blockIdx.x * 16;

    {
        const float4* W4 = (const float4*)W;
        float4* Wl4 = (float4*)Wl;
        #pragma unroll
        for (int m = 0; m < 16; ++m) Wl4[t + m * 256] = W4[t + m * 256];
    }
    {
        const float4* gb4 = (const float4*)gb;
        float4* inl4 = (float4*)inl;
        #pragma unroll
        for (int m = 0; m < 4; ++m) {
            const int c = m * 256 + t;
            const int r = c >> 5;
            const size_t grow = (r < 16) ? (size_t)(b0 + r) : (size_t)(B + b0 + r - 16);
            inl4[c] = gb4[grow * 32 + (c & 31)];
        }
    }
    __syncthreads();

    const int c0 = (t & 31) * 4;
    const int r0 = (t >> 5) * 4;

    float acc[4][4];
    {
        float4 bv = *(const float4*)&bias[c0];
        #pragma unroll
        for (int i = 0; i < 4; ++i) {
            acc[i][0] = bv.x; acc[i][1] = bv.y; acc[i][2] = bv.z; acc[i][3] = bv.w;
        }
    }

    for (int k = 0; k < 128; k += 4) {
        float4 a[4], w[4];
        #pragma unroll
        for (int i = 0; i < 4; ++i) a[i] = *(const float4*)&inl[(r0 + i) * D + k];
        #pragma unroll
        for (int kk = 0; kk < 4; ++kk) w[kk] = *(const float4*)&Wl[(k + kk) * D + c0];
        #pragma unroll
        for (int i = 0; i < 4; ++i) {
            const float* ai = (const float*)&a[i];
            #pragma unroll
            for (int kk = 0; kk < 4; ++kk) {
                acc[i][0] = fmaf(ai[kk], w[kk].x, acc[i][0]);
                acc[i][1] = fmaf(ai[kk], w[kk].y, acc[i][1]);
                acc[i][2] = fmaf(ai[kk], w[kk].z, acc[i][2]);
                acc[i][3] = fmaf(ai[kk], w[kk].w, acc[i][3]);
            }
        }
    }

    const int seg = (r0 < 16) ? 128 : 0;
    const float4 wv = *(const float4*)&wl_w[seg + c0];
    float pr[4];
    #pragma unroll
    for (int i = 0; i < 4; ++i) {
        const int r = r0 + i;
        const size_t grow = (r < 16) ? (size_t)(b0 + r) : (size_t)(B + b0 + r - 16);
        const float4 ad = *(const float4*)&h0[grow * D + c0];
        float4 o;
        o.x = ad.x + (acc[i][0] >= 0.f ? acc[i][0] : 0.2f * acc[i][0]);
        o.y = ad.y + (acc[i][1] >= 0.f ? acc[i][1] : 0.2f * acc[i][1]);
        o.z = ad.z + (acc[i][2] >= 0.f ? acc[i][2] : 0.2f * acc[i][2]);
        o.w = ad.w + (acc[i][3] >= 0.f ? acc[i][3] : 0.2f * acc[i][3]);
        pr[i] = o.x * wv.x + o.y * wv.y + o.z * wv.z + o.w * wv.w;
    }
    #pragma unroll
    for (int off = 1; off <= 16; off <<= 1) {
        pr[0] += __shfl_xor(pr[0], off);
        pr[1] += __shfl_xor(pr[1], off);
        pr[2] += __shfl_xor(pr[2], off);
        pr[3] += __shfl_xor(pr[3], off);
    }
    if ((t & 31) == 0) {
        rowdot[r0]     = pr[0];
        rowdot[r0 + 1] = pr[1];
        rowdot[r0 + 2] = pr[2];
        rowdot[r0 + 3] = pr[3];
    }
    __syncthreads();
    if (t < 16) out[b0 + t] = wl_b[0] + rowdot[t + 16] + rowdot[t];
}

extern "C" void kernel_launch(void* const* d_in, const int* in_sizes, int n_in,
                              void* d_out, int out_size, void* d_ws, size_t ws_size,
                              hipStream_t stream) {
    const int*   u        = (const int*)d_in[0];
    const int*   ii       = (const int*)d_in[1];
    const int*   adj_e    = (const int*)d_in[2];
    const int*   adj_r    = (const int*)d_in[3];
    const float* embs     = (const float*)d_in[4];
    const float* rel_embs = (const float*)d_in[5];
    const float* gamma    = (const float*)d_in[6];
    const float* beta     = (const float*)d_in[7];
    const float* mean     = (const float*)d_in[8];
    const float* var      = (const float*)d_in[9];
    const float* Wr1_w    = (const float*)d_in[10];
    const float* Wr1_b    = (const float*)d_in[11];
    const float* W1_w     = (const float*)d_in[12];
    const float* W1_b     = (const float*)d_in[13];
    const float* wl_w     = (const float*)d_in[14];
    const float* wl_b     = (const float*)d_in[15];
    float* out = (float*)d_out;

    const int n_ent = in_sizes[2] / KNB;    // 200000
    const int nb1 = n_ent / 64;             // 3125

    char* p = (char*)d_ws;
    unsigned short* Etr = (unsigned short*)p;           p += (size_t)n_ent * D * 2;   // 51.2 MB
    unsigned short* Wt  = (unsigned short*)p;           p += (size_t)D * D * 2;       // 32 KB
    float* scale = (float*)p;                           p += D * 4;
    float* shift = (float*)p;                           p += D * 4;
    float* h0   = (float*)p;                            p += (size_t)2 * B * D * 4;
    float* hWb  = (float*)p;                            p += (size_t)2 * B * D * 4;
    float* gb   = (float*)p;

    // 1. Wt = bf16(Wr1^T); scale/shift = BN affine fold   (grid=1)
    prep<<<1, 256, 0, stream>>>(Wr1_w, Wt, gamma, beta, mean, var, scale, shift);
    // 2. Etr = bf16(embs @ Wr1 + b)  AND  h0 = bn(embs[{i,u}]), hW = h0 @ Wr1 + b
    gemm_etr<<<nb1 + (2 * B) / 64, 256, 0, stream>>>(embs, Wt, Wr1_b, Etr,
                                                     ii, u, scale, shift, h0, hWb, nb1);
    // 3. FM aggregation -> g = h0 + Nh
    aggregate<<<2 * B, 256, 0, stream>>>(ii, u, adj_e, adj_r, Etr, rel_embs, hWb, h0, gb);
    // 4. hfin = h0 + lrelu(g @ W1 + b) fused with out = [u_e,h]@wl + wl_b
    gemm_fin<<<B / 16, 256, 0, stream>>>(gb, W1_w, W1_b, h0, wl_w, wl_b, out);
}

// Round 9
// 68.574 us; speedup vs baseline: 1.1630x; 1.1630x over previous
//
#include <hip/hip_runtime.h>

#define B     4096
#define KNB   64
#define D     128
#define NREL  32
#define EPS   1e-5f

typedef __attribute__((ext_vector_type(8))) short bf16x8;
typedef __attribute__((ext_vector_type(4))) float f32x4;

__device__ inline unsigned short f2bf(float f) {
    unsigned u = __float_as_uint(f);
    return (unsigned short)((u + 0x7FFFu + ((u >> 16) & 1u)) >> 16);
}
// HW packed convert, RTNE — bit-identical to f2bf, 1 VALU op per 2 floats.
__device__ inline unsigned cvt_pk_bf16(float lo, float hi) {
    unsigned r;
    asm("v_cvt_pk_bf16_f32 %0, %1, %2" : "=v"(r) : "v"(lo), "v"(hi));
    return r;
}
__device__ inline unsigned short cvt1_bf16(float f) {
    return (unsigned short)(cvt_pk_bf16(f, f) & 0xFFFFu);
}
__device__ inline float bfu_lo(unsigned u) { return __uint_as_float(u << 16); }
__device__ inline float bfu_hi(unsigned u) { return __uint_as_float(u & 0xFFFF0000u); }

// tanh(x) = 1 - 2/(exp(2x)+1), exp via native v_exp_f32. |err| ~1e-6.
__device__ inline float fast_tanh(float x) {
    float e = __builtin_amdgcn_exp2f(x * 2.885390082f);   // 2*log2(e)
    return 1.f - 2.f * __builtin_amdgcn_rcpf(e + 1.f);
}

// ---------------------------------------------------------------------------
// prep (8 blocks): Wt[n][k] = bf16(W[k][n]) with COALESCED 16B writes
// (reads strided, L2-hot — W is 64 KB). Block 0 also folds BN affine.
// ---------------------------------------------------------------------------
__global__ __launch_bounds__(256) void prep(
    const float* __restrict__ W, unsigned short* __restrict__ Wt,
    const float* __restrict__ gamma, const float* __restrict__ beta,
    const float* __restrict__ mean,  const float* __restrict__ var,
    float* __restrict__ scale, float* __restrict__ shift)
{
    const int t = threadIdx.x;
    const int g = blockIdx.x * 256 + t;   // 0..2047
    const int n  = g >> 4;                // output row
    const int k0 = (g & 15) * 8;          // 8 consecutive k
    unsigned short h[8];
    #pragma unroll
    for (int i = 0; i < 8; ++i) h[i] = f2bf(W[(k0 + i) * D + n]);
    *(uint4*)&Wt[(size_t)n * D + k0] = *(const uint4*)h;

    if (blockIdx.x == 0 && t < D) {
        const float sc = gamma[t] * rsqrtf(var[t] + EPS);
        scale[t] = sc;
        shift[t] = beta[t] - mean[t] * sc;
    }
}

// ---------------------------------------------------------------------------
// MFMA GEMM, 16x16x32 bf16, tile 64 rows x 128 cols, 4 waves.
// blocks <  nb1 : Etr = bf16( embs @ W + bias )        (bf16 bounce-store)
// blocks >= nb1 : h0  = bn(embs[{i,u}]) (f32, stored)  AND
//                 hW  = h0 @ W + bias   (f32 direct store)
// ---------------------------------------------------------------------------
__global__ __launch_bounds__(256) void gemm_etr(
    const float* __restrict__ embs, const unsigned short* __restrict__ Wt,
    const float* __restrict__ bias, unsigned short* __restrict__ outbf,
    const int* __restrict__ i_idx, const int* __restrict__ u_idx,
    const float* __restrict__ scale, const float* __restrict__ shift,
    float* __restrict__ h0out, float* __restrict__ out2, int nb1)
{
    __shared__ unsigned short Al[64 * 128];    // 16 KB
    __shared__ unsigned short Wl[128 * 128];   // 32 KB

    const int t = threadIdx.x;
    const bool second = (int)blockIdx.x >= nb1;
    const size_t row0 = (size_t)(second ? (int)blockIdx.x - nb1 : (int)blockIdx.x) * 64;

    {
        const float4* w4 = (const float4*)Wt;
        #pragma unroll
        for (int m = 0; m < 8; ++m) {
            const int c = m * 256 + t;
            const int n = c >> 4;
            float4 v = w4[c];
            *(float4*)((char*)Wl + ((c * 16) ^ ((n & 7) << 4))) = v;
        }
    }
    if (!second) {
        #pragma unroll
        for (int m = 0; m < 4; ++m) {
            const int c = m * 256 + t;
            const int r = c >> 4;
            const int k0 = (c & 15) * 8;
            const float4* s = (const float4*)&embs[(row0 + r) * D + k0];
            const float4 x = s[0], y = s[1];
            uint4 h;
            h.x = cvt_pk_bf16(x.x, x.y);
            h.y = cvt_pk_bf16(x.z, x.w);
            h.z = cvt_pk_bf16(y.x, y.y);
            h.w = cvt_pk_bf16(y.z, y.w);
            *(uint4*)((char*)Al + ((r * 256 + k0 * 2) ^ ((r & 7) << 4))) = h;
        }
    } else {
        // bn-fold: gather embs[idx_j[b]], apply scale/shift, store h0, stage bf16
        #pragma unroll
        for (int m = 0; m < 4; ++m) {
            const int c = m * 256 + t;
            const int r = c >> 4;
            const int k0 = (c & 15) * 8;
            const int grow = (int)row0 + r;              // 0 .. 2B-1
            const int bb = grow & (B - 1);
            const int idxv = (grow >= B) ? u_idx[bb] : i_idx[bb];
            const float4* s = (const float4*)&embs[(size_t)idxv * D + k0];
            const float4 x = s[0], y = s[1];
            const float4 sc0 = *(const float4*)&scale[k0];
            const float4 sc1 = *(const float4*)&scale[k0 + 4];
            const float4 sh0 = *(const float4*)&shift[k0];
            const float4 sh1 = *(const float4*)&shift[k0 + 4];
            float4 a0, a1;
            a0.x = fmaf(x.x, sc0.x, sh0.x); a0.y = fmaf(x.y, sc0.y, sh0.y);
            a0.z = fmaf(x.z, sc0.z, sh0.z); a0.w = fmaf(x.w, sc0.w, sh0.w);
            a1.x = fmaf(y.x, sc1.x, sh1.x); a1.y = fmaf(y.y, sc1.y, sh1.y);
            a1.z = fmaf(y.z, sc1.z, sh1.z); a1.w = fmaf(y.w, sc1.w, sh1.w);
            *(float4*)&h0out[(size_t)grow * D + k0]     = a0;
            *(float4*)&h0out[(size_t)grow * D + k0 + 4] = a1;
            uint4 h;
            h.x = cvt_pk_bf16(a0.x, a0.y);
            h.y = cvt_pk_bf16(a0.z, a0.w);
            h.z = cvt_pk_bf16(a1.x, a1.y);
            h.w = cvt_pk_bf16(a1.z, a1.w);
            *(uint4*)((char*)Al + ((r * 256 + k0 * 2) ^ ((r & 7) << 4))) = h;
        }
    }
    __syncthreads();

    const int wv   = t >> 6;
    const int lane = t & 63;
    const int rw   = wv * 16;
    const int lrow = lane & 15;
    const int kgrp = lane >> 4;

    f32x4 acc[8];
    #pragma unroll
    for (int n = 0; n < 8; ++n) acc[n] = (f32x4){0.f, 0.f, 0.f, 0.f};

    #pragma unroll
    for (int ks = 0; ks < 4; ++ks) {
        const int arow = rw + lrow;
        const bf16x8 a = *(const bf16x8*)((const char*)Al +
            ((arow * 256 + ks * 64 + kgrp * 16) ^ ((arow & 7) << 4)));
        #pragma unroll
        for (int n = 0; n < 8; ++n) {
            const int brow = n * 16 + lrow;
            const bf16x8 b = *(const bf16x8*)((const char*)Wl +
                ((brow * 256 + ks * 64 + kgrp * 16) ^ ((brow & 7) << 4)));
            acc[n] = __builtin_amdgcn_mfma_f32_16x16x32_bf16(a, b, acc[n], 0, 0, 0);
        }
    }

    // C/D layout: col = lane&15, row = (lane>>4)*4 + i
    if (second) {   // hW f32 direct store
        #pragma unroll
        for (int n = 0; n < 8; ++n) {
            const float bv = bias[n * 16 + lrow];
            #pragma unroll
            for (int i = 0; i < 4; ++i) {
                const size_t r = row0 + rw + kgrp * 4 + i;
                out2[r * D + n * 16 + lrow] = acc[n][i] + bv;
            }
        }
        return;
    }

    __syncthreads();
    #pragma unroll
    for (int n = 0; n < 8; ++n) {
        const float bv = bias[n * 16 + lrow];
        #pragma unroll
        for (int i = 0; i < 4; ++i) {
            const int r = rw + kgrp * 4 + i;
            const int cb = (r * 256 + (n * 16 + lrow) * 2) ^ ((r & 7) << 4);
            *(unsigned short*)((char*)Al + cb) = cvt1_bf16(acc[n][i] + bv);
        }
    }
    __syncthreads();
    {
        float4* dst = (float4*)(outbf + row0 * D);
        #pragma unroll
        for (int m = 0; m < 4; ++m) {
            const int c = m * 256 + t;
            const int r = c >> 4;
            dst[c] = *(const float4*)((const char*)Al + ((c * 16) ^ ((r & 7) << 4)));
        }
    }
}

// ---------------------------------------------------------------------------
// aggregate v7: (256,8) forces VGPR<=64 -> 8 blocks/CU (LDS 16.5 KB).
// Gathers issue before tanh table; ps/pq alias dead tt space.
// ---------------------------------------------------------------------------
__global__ __launch_bounds__(256, 8) void aggregate(
    const int* __restrict__ i_idx, const int* __restrict__ u_idx,
    const int* __restrict__ adj_e, const int* __restrict__ adj_r,
    const unsigned short* __restrict__ Etr, const float* __restrict__ rel_embs,
    const float* __restrict__ hW,  const float* __restrict__ h0,
    float* __restrict__ g_out)
{
    __shared__ float tt[NREL * D];    // 16 KB; reused for ps/pq after main loop
    __shared__ int ents[KNB];
    __shared__ int rels[KNB];
    float* ps = tt;                   // [4][D]
    float* pq = tt + 4 * D;           // [4][D]

    const int t = threadIdx.x;
    const int b = blockIdx.x & (B - 1);
    const int j = blockIdx.x >> 12;
    const size_t rowbase = ((size_t)j * B + b) * D;
    const int idx = j ? u_idx[b] : i_idx[b];

    const float4 hv = *(const float4*)&hW[rowbase + (t & 31) * 4];
    float h0v = 0.f;
    if (t < D) h0v = h0[rowbase + t];

    if (t < KNB) {
        ents[t] = adj_e[(size_t)idx * KNB + t] * (D * 2);
        rels[t] = adj_r[(size_t)idx * KNB + t] * (D * 4);
    }
    __syncthreads();   // ents/rels ready

    const int dq  = t & 31;
    const int grp = t >> 5;
    const char* Eb = (const char*)Etr + dq * 8;
    const char* tb = (const char*)tt  + dq * 16;

    // issue ALL 8 random gathers; latency hides under the tanh-table pass.
    uint2 ev[8];
    #pragma unroll
    for (int it = 0; it < 8; ++it)
        ev[it] = *(const uint2*)(Eb + ents[grp + it * 8]);

    {
        const float4* re4 = (const float4*)rel_embs;
        #pragma unroll
        for (int c = 0; c < 4; ++c) {
            const int m4 = t + c * 256;
            const float4 r = re4[m4];
            float4 o;
            o.x = fast_tanh(hv.x + r.x);
            o.y = fast_tanh(hv.y + r.y);
            o.z = fast_tanh(hv.z + r.z);
            o.w = fast_tanh(hv.w + r.w);
            *(float4*)&tt[m4 * 4] = o;
        }
    }
    __syncthreads();   // tt ready

    float s0 = 0.f, s1 = 0.f, s2 = 0.f, s3 = 0.f;
    float q0 = 0.f, q1 = 0.f, q2 = 0.f, q3 = 0.f;
    #pragma unroll
    for (int it = 0; it < 8; ++it) {
        const float4 tv = *(const float4*)(tb + rels[grp + it * 8]);
        const float v0 = bfu_lo(ev[it].x) * tv.x;
        const float v1 = bfu_hi(ev[it].x) * tv.y;
        const float v2 = bfu_lo(ev[it].y) * tv.z;
        const float v3 = bfu_hi(ev[it].y) * tv.w;
        s0 += v0; s1 += v1; s2 += v2; s3 += v3;
        q0 = fmaf(v0, v0, q0); q1 = fmaf(v1, v1, q1);
        q2 = fmaf(v2, v2, q2); q3 = fmaf(v3, v3, q3);
    }
    s0 += __shfl_xor(s0, 32); s1 += __shfl_xor(s1, 32);
    s2 += __shfl_xor(s2, 32); s3 += __shfl_xor(s3, 32);
    q0 += __shfl_xor(q0, 32); q1 += __shfl_xor(q1, 32);
    q2 += __shfl_xor(q2, 32); q3 += __shfl_xor(q3, 32);

    __syncthreads();   // all tt reads done; safe to overwrite with ps/pq

    const int wv = t >> 6;
    if ((t & 63) < 32) {
        *(float4*)&ps[wv * D + dq * 4] = make_float4(s0, s1, s2, s3);
        *(float4*)&pq[wv * D + dq * 4] = make_float4(q0, q1, q2, q3);
    }
    __syncthreads();

    if (t < D) {
        const float ss = ps[t] + ps[D + t] + ps[2 * D + t] + ps[3 * D + t];
        const float qq = pq[t] + pq[D + t] + pq[2 * D + t] + pq[3 * D + t];
        g_out[rowbase + t] = h0v + ss * ss - qq;
    }
}

// ---------------------------------------------------------------------------
// gemm_fin: 16 b-pairs/block; W1 staged in TWO 64-row K-chunks (32 KB) ->
// LDS 48 KB -> 3 blocks/CU (was 2). Epilogue fuses final wl dot.
// ---------------------------------------------------------------------------
__global__ __launch_bounds__(256) void gemm_fin(
    const float* __restrict__ gb, const float* __restrict__ W,
    const float* __restrict__ bias, const float* __restrict__ h0,
    const float* __restrict__ wl_w, const float* __restrict__ wl_b,
    float* __restrict__ out)
{
    __shared__ float Wl[64 * 128];    // 32 KB (one K-chunk)
    __shared__ float inl[32 * 128];   // 16 KB
    __shared__ float rowdot[32];
    const int t = threadIdx.x;
    const int b0 = blockIdx.x * 16;

    {
        const float4* gb4 = (const float4*)gb;
        float4* inl4 = (float4*)inl;
        #pragma unroll
        for (int m = 0; m < 4; ++m) {
            const int c = m * 256 + t;
            const int r = c >> 5;
            const size_t grow = (r < 16) ? (size_t)(b0 + r) : (size_t)(B + b0 + r - 16);
            inl4[c] = gb4[grow * 32 + (c & 31)];
        }
    }

    const int c0 = (t & 31) * 4;
    const int r0 = (t >> 5) * 4;

    float acc[4][4];
    {
        float4 bv = *(const float4*)&bias[c0];
        #pragma unroll
        for (int i = 0; i < 4; ++i) {
            acc[i][0] = bv.x; acc[i][1] = bv.y; acc[i][2] = bv.z; acc[i][3] = bv.w;
        }
    }

    #pragma unroll
    for (int chunk = 0; chunk < 2; ++chunk) {
        __syncthreads();   // inl ready (iter 0) / prior chunk's reads done
        {
            const float4* W4 = (const float4*)(W + chunk * 64 * D);
            float4* Wl4 = (float4*)Wl;
            #pragma unroll
            for (int m = 0; m < 8; ++m) Wl4[t + m * 256] = W4[t + m * 256];
        }
        __syncthreads();
        for (int k = 0; k < 64; k += 4) {
            float4 a[4], w[4];
            #pragma unroll
            for (int i = 0; i < 4; ++i)
                a[i] = *(const float4*)&inl[(r0 + i) * D + chunk * 64 + k];
            #pragma unroll
            for (int kk = 0; kk < 4; ++kk)
                w[kk] = *(const float4*)&Wl[(k + kk) * D + c0];
            #pragma unroll
            for (int i = 0; i < 4; ++i) {
                const float* ai = (const float*)&a[i];
                #pragma unroll
                for (int kk = 0; kk < 4; ++kk) {
                    acc[i][0] = fmaf(ai[kk], w[kk].x, acc[i][0]);
                    acc[i][1] = fmaf(ai[kk], w[kk].y, acc[i][1]);
                    acc[i][2] = fmaf(ai[kk], w[kk].z, acc[i][2]);
                    acc[i][3] = fmaf(ai[kk], w[kk].w, acc[i][3]);
                }
            }
        }
    }

    const int seg = (r0 < 16) ? 128 : 0;
    const float4 wv = *(const float4*)&wl_w[seg + c0];
    float pr[4];
    #pragma unroll
    for (int i = 0; i < 4; ++i) {
        const int r = r0 + i;
        const size_t grow = (r < 16) ? (size_t)(b0 + r) : (size_t)(B + b0 + r - 16);
        const float4 ad = *(const float4*)&h0[grow * D + c0];
        float4 o;
        o.x = ad.x + (acc[i][0] >= 0.f ? acc[i][0] : 0.2f * acc[i][0]);
        o.y = ad.y + (acc[i][1] >= 0.f ? acc[i][1] : 0.2f * acc[i][1]);
        o.z = ad.z + (acc[i][2] >= 0.f ? acc[i][2] : 0.2f * acc[i][2]);
        o.w = ad.w + (acc[i][3] >= 0.f ? acc[i][3] : 0.2f * acc[i][3]);
        pr[i] = o.x * wv.x + o.y * wv.y + o.z * wv.z + o.w * wv.w;
    }
    #pragma unroll
    for (int off = 1; off <= 16; off <<= 1) {
        pr[0] += __shfl_xor(pr[0], off);
        pr[1] += __shfl_xor(pr[1], off);
        pr[2] += __shfl_xor(pr[2], off);
        pr[3] += __shfl_xor(pr[3], off);
    }
    if ((t & 31) == 0) {
        rowdot[r0]     = pr[0];
        rowdot[r0 + 1] = pr[1];
        rowdot[r0 + 2] = pr[2];
        rowdot[r0 + 3] = pr[3];
    }
    __syncthreads();
    if (t < 16) out[b0 + t] = wl_b[0] + rowdot[t + 16] + rowdot[t];
}

extern "C" void kernel_launch(void* const* d_in, const int* in_sizes, int n_in,
                              void* d_out, int out_size, void* d_ws, size_t ws_size,
                              hipStream_t stream) {
    const int*   u        = (const int*)d_in[0];
    const int*   ii       = (const int*)d_in[1];
    const int*   adj_e    = (const int*)d_in[2];
    const int*   adj_r    = (const int*)d_in[3];
    const float* embs     = (const float*)d_in[4];
    const float* rel_embs = (const float*)d_in[5];
    const float* gamma    = (const float*)d_in[6];
    const float* beta     = (const float*)d_in[7];
    const float* mean     = (const float*)d_in[8];
    const float* var      = (const float*)d_in[9];
    const float* Wr1_w    = (const float*)d_in[10];
    const float* Wr1_b    = (const float*)d_in[11];
    const float* W1_w     = (const float*)d_in[12];
    const float* W1_b     = (const float*)d_in[13];
    const float* wl_w     = (const float*)d_in[14];
    const float* wl_b     = (const float*)d_in[15];
    float* out = (float*)d_out;

    const int n_ent = in_sizes[2] / KNB;    // 200000
    const int nb1 = n_ent / 64;             // 3125

    char* p = (char*)d_ws;
    unsigned short* Etr = (unsigned short*)p;           p += (size_t)n_ent * D * 2;   // 51.2 MB
    unsigned short* Wt  = (unsigned short*)p;           p += (size_t)D * D * 2;       // 32 KB
    float* scale = (float*)p;                           p += D * 4;
    float* shift = (float*)p;                           p += D * 4;
    float* h0   = (float*)p;                            p += (size_t)2 * B * D * 4;
    float* hWb  = (float*)p;                            p += (size_t)2 * B * D * 4;
    float* gb   = (float*)p;

    // 1. Wt = bf16(Wr1^T) (coalesced writes, 8 blocks); BN affine fold
    prep<<<8, 256, 0, stream>>>(Wr1_w, Wt, gamma, beta, mean, var, scale, shift);
    // 2. Etr = bf16(embs @ Wr1 + b)  AND  h0 = bn(embs[{i,u}]), hW = h0 @ Wr1 + b
    gemm_etr<<<nb1 + (2 * B) / 64, 256, 0, stream>>>(embs, Wt, Wr1_b, Etr,
                                                     ii, u, scale, shift, h0, hWb, nb1);
    // 3. FM aggregation -> g = h0 + Nh
    aggregate<<<2 * B, 256, 0, stream>>>(ii, u, adj_e, adj_r, Etr, rel_embs, hWb, h0, gb);
    // 4. hfin = h0 + lrelu(g @ W1 + b) fused with out = [u_e,h]@wl + wl_b
    gemm_fin<<<B / 16, 256, 0, stream>>>(gb, W1_w, W1_b, h0, wl_w, wl_b, out);
}